// Round 6
// baseline (485.623 us; speedup 1.0000x reference)
//
#include <hip/hip_runtime.h>
#include <hip/hip_bf16.h>

#define BATCH 8
#define NN    2048
#define FIN   512
#define FOUT  32
#define GALPHA 0.2f
#define NIT   32          // 2048/64 k-intervals

typedef float  f32x4  __attribute__((ext_vector_type(4)));
typedef __bf16 bf16x8 __attribute__((ext_vector_type(8)));
typedef unsigned short u16;
typedef u16 u16x8 __attribute__((ext_vector_type(8)));

static __device__ __forceinline__ u16 f2bf(float f) {
    __hip_bfloat16 h = __float2bfloat16(f);
    union { __hip_bfloat16 h; u16 u; } c; c.h = h; return c.u;
}
static __device__ __forceinline__ float bf2f(u16 u) {
    union { u16 u; __hip_bfloat16 h; } c; c.u = u; return __bfloat162float(c.h);
}

// K_prep v4 (UNCHANGED, verified R4): grid 2048 x 256 — one block per
// (b, mt, it) 64x64 chunk. w1/w2 inlined; xtf transpose + f1/f2 atomics;
// LDS-staged contiguous adj pack (bit layout identical to verified k_pack).
__global__ __launch_bounds__(256) void k_prep(
    const float* __restrict__ x, const int* __restrict__ adj,
    const float* __restrict__ Wfc, const float* __restrict__ Wat,
    __hip_bfloat16* __restrict__ xt,
    float* __restrict__ f1, float* __restrict__ f2,
    unsigned int* __restrict__ bits)
{
    const int bx = blockIdx.x;
    const int it = bx & 7, mt = (bx >> 3) & 31, b = bx >> 8;
    const int m0 = mt * 64, i0 = it * 64;
    const int tt = threadIdx.x;

    __shared__ __align__(16) char smem[16384];
    u16 (*tile)[72]   = (u16(*)[72])smem;
    float* w1s        = (float*)(smem + 9216);
    float* w2s        = (float*)(smem + 9216 + 256);
    unsigned int* pls = (unsigned int*)smem;

    if (tt < 64) {
        const int i = i0 + tt;
        float s1 = 0.f, s2 = 0.f;
        #pragma unroll
        for (int o = 0; o < FOUT; o++) {
            float wv = Wfc[o * FIN + i];
            s1 += wv * Wat[o];
            s2 += wv * Wat[FOUT + o];
        }
        w1s[tt] = s1; w2s[tt] = s2;
    }
    __syncthreads();

    const int mm  = tt >> 3;         // 0..31
    const int icl = (tt & 7) * 8;    // 0..56
    const float* xb = x + ((size_t)b * NN + m0) * FIN + i0;
    f32x4 wA = *(const f32x4*)&w1s[icl];
    f32x4 wB = *(const f32x4*)&w1s[icl + 4];
    f32x4 wC = *(const f32x4*)&w2s[icl];
    f32x4 wD = *(const f32x4*)&w2s[icl + 4];
    float p1[2], p2[2];
    #pragma unroll
    for (int h = 0; h < 2; h++) {
        int m = mm + h * 32;
        const f32x4* src = (const f32x4*)(xb + (size_t)m * FIN + icl);
        f32x4 v0 = src[0], v1 = src[1];
        u16x8 pk;
        float s1 = 0.f, s2 = 0.f;
        #pragma unroll
        for (int j = 0; j < 4; j++) {
            pk[j] = f2bf(v0[j]); pk[4 + j] = f2bf(v1[j]);
            s1 += v0[j] * wA[j] + v1[j] * wB[j];
            s2 += v0[j] * wC[j] + v1[j] * wD[j];
        }
        p1[h] = s1; p2[h] = s2;
        *(u16x8*)&tile[m][icl] = pk;
    }
    #pragma unroll
    for (int off = 1; off < 8; off <<= 1) {
        p1[0] += __shfl_xor(p1[0], off); p1[1] += __shfl_xor(p1[1], off);
        p2[0] += __shfl_xor(p2[0], off); p2[1] += __shfl_xor(p2[1], off);
    }
    if ((tt & 7) == 0) {
        size_t r0 = (size_t)b * NN + m0 + mm;
        atomicAdd(&f1[r0], p1[0]);      atomicAdd(&f1[r0 + 32], p1[1]);
        atomicAdd(&f2[r0], p2[0]);      atomicAdd(&f2[r0 + 32], p2[1]);
    }
    __syncthreads();
    __hip_bfloat16* xtb = xt + ((size_t)b * FIN + i0) * NN + m0;
    const int mc = (tt & 7) * 8;
    #pragma unroll
    for (int h = 0; h < 2; h++) {
        int ii = (tt >> 3) + h * 32;
        u16x8 v;
        #pragma unroll
        for (int j = 0; j < 8; j++) v[j] = tile[mc + j][ii];
        *(u16x8*)(xtb + (size_t)ii * NN + mc) = v;
    }

    __syncthreads();   // tile LDS is dead; reuse as predicate staging
    {
        const int* ab = adj + (size_t)(b * NN + m0 + it * 8) * NN;
        #pragma unroll
        for (int s = 0; s < 16; s++) {
            int4 v = *(const int4*)(ab + (size_t)(s * 256 + tt) * 4);
            unsigned int pb = (v.x != 0 ? 0x00000001u : 0u)
                            | (v.y != 0 ? 0x00000100u : 0u)
                            | (v.z != 0 ? 0x00010000u : 0u)
                            | (v.w != 0 ? 0x01000000u : 0u);
            pls[s * 256 + tt] = pb;
        }
        __syncthreads();
        const int r = tt >> 5, c0 = tt & 31;
        #pragma unroll
        for (int half = 0; half < 2; half++) {
            const int c = c0 + half * 32;
            const unsigned int* q = pls + r * 512 + c * 8;
            unsigned int bv = 0;
            #pragma unroll
            for (int j = 0; j < 8; j++) {
                unsigned int pb = q[j];
                bv |= (pb         & 1u) << (j * 4 + 0);
                bv |= ((pb >> 8)  & 1u) << (j * 4 + 1);
                bv |= ((pb >> 16) & 1u) << (j * 4 + 2);
                bv |= ((pb >> 24) & 1u) << (j * 4 + 3);
            }
            bits[(size_t)(b * NN + m0 + it * 8 + r) * 64 + c] = bv;
        }
    }
}

// K3 v3: barrier-free fused attn-gen + GEMM + softmax + ELU.
// Each lane computes its OWN MFMA A-fragment in registers:
//   A layout (verified by R4's At read): row = lane&15, k = quad*8+j (+32/ks)
//   -> gen is lane-local: exp(leaky(f1[row] + f2[k])) * adjbit. No LDS,
//      no s_barrier, no lgkmcnt in the K-loop; 8 independent waves/block.
// Geometry: wave = 16 rows x 128 cols; block = 8 waves = 128 rows x 128 cols;
// grid 512 = 4 it x 16 rt x 8 b (b = bx&7 -> XCD affinity, xt slice L2-local).
// Rowsum: lane partial is row-pure (row=l15) -> shfl_xor(16,32), then
// dynamic __shfl redistributes inv to C-layout rows (quad*4+r).
__global__ __launch_bounds__(512, 3) void k_main(
    const unsigned int* __restrict__ bits, const __hip_bfloat16* __restrict__ xt,
    const float* __restrict__ f1, const float* __restrict__ f2,
    float* __restrict__ out)
{
    const int bx = blockIdx.x;
    const int b = bx & 7, rt = (bx >> 3) & 15, it = bx >> 7;   // it 0..3
    const int n0 = rt * 128;
    const int i0 = it * 128;
    const int tid = threadIdx.x;
    const int lane = tid & 63, wv = tid >> 6;                  // 8 waves
    const int quad = lane >> 4, l15 = lane & 15;

    const int row = n0 + wv * 16 + l15;            // this lane's P-row
    const float f1v = f1[b * NN + row];
    // bits: byte n of a row covers cols n*8..n*8+7 (verified layout).
    // per iter t we need bytes t*8 + ks*4 + quad  ->  one uint2 per iter.
    const uint2* bpr = (const uint2*)((const unsigned char*)bits
                                      + ((size_t)(b * NN) + row) * 256);
    // f2: per (t, ks) lane needs f2[t*64 + ks*32 + quad*8 + (0..7)]
    const float* f2b = f2 + b * NN + quad * 8;
    // B: lane reads xt[(b*FIN + i0 + c*16 + l15)*NN + t*64 + ks*32 + quad*8]
    const __hip_bfloat16* xtp = xt + ((size_t)(b * FIN) + i0 + l15) * NN + quad * 8;

    f32x4 acc[8];
    #pragma unroll
    for (int c = 0; c < 8; c++) acc[c] = (f32x4){0, 0, 0, 0};

    float rpart = 0.f;

    // 1-deep prefetch ring: adjacency uint2 + 4x f32x4 of f2
    uint2 bv_n = bpr[0];
    f32x4 f2n0 = *(const f32x4*)(f2b);
    f32x4 f2n1 = *(const f32x4*)(f2b + 4);
    f32x4 f2n2 = *(const f32x4*)(f2b + 32);
    f32x4 f2n3 = *(const f32x4*)(f2b + 36);

    #pragma unroll 2
    for (int t = 0; t < NIT; t++) {
        const uint2 bw = bv_n;
        const f32x4 fA = f2n0, fB = f2n1, fC = f2n2, fD = f2n3;
        if (t < NIT - 1) {
            bv_n = bpr[t + 1];
            const float* fp = f2b + (t + 1) * 64;
            f2n0 = *(const f32x4*)(fp);
            f2n1 = *(const f32x4*)(fp + 4);
            f2n2 = *(const f32x4*)(fp + 32);
            f2n3 = *(const f32x4*)(fp + 36);
        }
        #pragma unroll
        for (int ks = 0; ks < 2; ks++) {
            // B fragments for this half-interval (8 col-tiles)
            const __hip_bfloat16* xk = xtp + t * 64 + ks * 32;
            bf16x8 Bf[8];
            #pragma unroll
            for (int c = 0; c < 8; c++)
                Bf[c] = *(const bf16x8*)(xk + (size_t)(c * 16) * NN);
            // gen this lane's A-fragment (8 elems, k = quad*8+j)
            const unsigned int byte = ((ks ? bw.y : bw.x) >> (quad * 8)) & 0xffu;
            const f32x4 f0 = ks ? fC : fA;
            const f32x4 f1r = ks ? fD : fB;
            union { u16x8 u; bf16x8 h; } a;
            #pragma unroll
            for (int e = 0; e < 8; e++) {
                float s  = f1v + (e < 4 ? f0[e & 3] : f1r[e & 3]);
                float ls = fmaxf(s, GALPHA * s);               // leaky_relu
                float ev = ((byte >> e) & 1u) ? __expf(ls) : 0.f;
                u16 hb = f2bf(ev);
                rpart += bf2f(hb);                             // rowsum of bf16-rounded
                a.u[e] = hb;
            }
            #pragma unroll
            for (int c = 0; c < 8; c++)
                acc[c] = __builtin_amdgcn_mfma_f32_16x16x32_bf16(a.h, Bf[c], acc[c], 0, 0, 0);
        }
    }

    // rowsum: lanes {l15, l15+16, l15+32, l15+48} hold disjoint k-slices of row l15
    rpart += __shfl_xor(rpart, 16);
    rpart += __shfl_xor(rpart, 32);
    const float inv = 1.0f / rpart;    // valid in every lane for row l15

    // epilogue: C/D layout row = quad*4+r, col = l15. Pull inv for that row
    // from lane (quad*4+r) via dynamic shfl; normalize, ELU, store fp32.
    #pragma unroll
    for (int r = 0; r < 4; r++) {
        const float invr = __shfl(inv, quad * 4 + r);
        float* op = out + ((size_t)b * NN + n0 + wv * 16 + quad * 4 + r) * FIN + i0 + l15;
        #pragma unroll
        for (int c = 0; c < 8; c++) {
            float v = acc[c][r] * invr;
            v = v > 0.f ? v : (__expf(v) - 1.f);   // elu
            op[c * 16] = v;
        }
    }
}

extern "C" void kernel_launch(void* const* d_in, const int* in_sizes, int n_in,
                              void* d_out, int out_size, void* d_ws, size_t ws_size,
                              hipStream_t stream) {
    const float* x   = (const float*)d_in[0];
    const int*   adj = (const int*)d_in[1];
    const float* Wfc = (const float*)d_in[2];
    const float* Wat = (const float*)d_in[3];
    float* out = (float*)d_out;

    float* f1 = (float*)d_ws;                                   // 16384
    float* f2 = f1 + BATCH * NN;                                // 16384
    unsigned int* bits = (unsigned int*)(f2 + BATCH * NN);      // 16384*64 u32 = 4.2 MB
    __hip_bfloat16* xt = (__hip_bfloat16*)(bits + (size_t)BATCH * NN * 64);  // 16.8 MB

    hipMemsetAsync(f1, 0, (size_t)2 * BATCH * NN * sizeof(float), stream);
    hipLaunchKernelGGL(k_prep, dim3(2048), dim3(256), 0, stream,
                       x, adj, Wfc, Wat, xt, f1, f2, bits);
    hipLaunchKernelGGL(k_main, dim3(512),  dim3(512), 0, stream,
                       bits, xt, f1, f2, out);
}

// Round 7
// 288.105 us; speedup vs baseline: 1.6856x; 1.6856x over previous
//
#include <hip/hip_runtime.h>
#include <hip/hip_bf16.h>

#define BATCH 8
#define NN    2048
#define FIN   512
#define FOUT  32
#define GALPHA 0.2f
#define NROW  128         // n-rows per k_main block
#define NIT   32          // 2048/64 k-intervals

typedef float  f32x4  __attribute__((ext_vector_type(4)));
typedef __bf16 bf16x8 __attribute__((ext_vector_type(8)));
typedef unsigned short u16;
typedef u16 u16x8 __attribute__((ext_vector_type(8)));

static __device__ __forceinline__ u16 f2bf(float f) {
    __hip_bfloat16 h = __float2bfloat16(f);
    union { __hip_bfloat16 h; u16 u; } c; c.h = h; return c.u;
}
static __device__ __forceinline__ float bf2f(u16 u) {
    union { u16 u; __hip_bfloat16 h; } c; c.u = u; return __bfloat162float(c.h);
}

// K_prep v5: R4's verified v4 + issue-early adj loads (T14 split).
// The 134 MB adj stream is issued into registers at kernel entry and pinned
// there with sched_barrier(0); it streams from HBM UNDER the w12+transpose
// phases instead of starting after them. Convert/pack (LDS-staged, verified
// bit layout) runs after the last transpose barrier. +64 VGPR (~100 total,
// 5 blocks/CU cap — above the ~3 measured resident, so not binding).
__global__ __launch_bounds__(256) void k_prep(
    const float* __restrict__ x, const int* __restrict__ adj,
    const float* __restrict__ Wfc, const float* __restrict__ Wat,
    __hip_bfloat16* __restrict__ xt,
    float* __restrict__ f1, float* __restrict__ f2,
    unsigned int* __restrict__ bits)
{
    const int bx = blockIdx.x;
    const int it = bx & 7, mt = (bx >> 3) & 31, b = bx >> 8;
    const int m0 = mt * 64, i0 = it * 64;
    const int tt = threadIdx.x;

    __shared__ __align__(16) char smem[16384];
    u16 (*tile)[72]   = (u16(*)[72])smem;
    float* w1s        = (float*)(smem + 9216);
    float* w2s        = (float*)(smem + 9216 + 256);
    unsigned int* pls = (unsigned int*)smem;

    // ---- issue adj loads FIRST (consumed after the transpose phase) ----
    const int* ab = adj + (size_t)(b * NN + m0 + it * 8) * NN;
    int4 av[16];
    #pragma unroll
    for (int s = 0; s < 16; s++)
        av[s] = *(const int4*)(ab + (size_t)(s * 256 + tt) * 4);
    __builtin_amdgcn_sched_barrier(0);   // pin issue point: don't sink loads

    // inline w1/w2 for this 64-wide i-chunk
    if (tt < 64) {
        const int i = i0 + tt;
        float s1 = 0.f, s2 = 0.f;
        #pragma unroll
        for (int o = 0; o < FOUT; o++) {
            float wv = Wfc[o * FIN + i];
            s1 += wv * Wat[o];
            s2 += wv * Wat[FOUT + o];
        }
        w1s[tt] = s1; w2s[tt] = s2;
    }
    __syncthreads();

    const int mm  = tt >> 3;         // 0..31
    const int icl = (tt & 7) * 8;    // 0..56
    const float* xb = x + ((size_t)b * NN + m0) * FIN + i0;
    f32x4 wA = *(const f32x4*)&w1s[icl];
    f32x4 wB = *(const f32x4*)&w1s[icl + 4];
    f32x4 wC = *(const f32x4*)&w2s[icl];
    f32x4 wD = *(const f32x4*)&w2s[icl + 4];
    float p1[2], p2[2];
    #pragma unroll
    for (int h = 0; h < 2; h++) {
        int m = mm + h * 32;
        const f32x4* src = (const f32x4*)(xb + (size_t)m * FIN + icl);
        f32x4 v0 = src[0], v1 = src[1];
        u16x8 pk;
        float s1 = 0.f, s2 = 0.f;
        #pragma unroll
        for (int j = 0; j < 4; j++) {
            pk[j] = f2bf(v0[j]); pk[4 + j] = f2bf(v1[j]);
            s1 += v0[j] * wA[j] + v1[j] * wB[j];
            s2 += v0[j] * wC[j] + v1[j] * wD[j];
        }
        p1[h] = s1; p2[h] = s2;
        *(u16x8*)&tile[m][icl] = pk;
    }
    #pragma unroll
    for (int off = 1; off < 8; off <<= 1) {
        p1[0] += __shfl_xor(p1[0], off); p1[1] += __shfl_xor(p1[1], off);
        p2[0] += __shfl_xor(p2[0], off); p2[1] += __shfl_xor(p2[1], off);
    }
    if ((tt & 7) == 0) {
        size_t r0 = (size_t)b * NN + m0 + mm;
        atomicAdd(&f1[r0], p1[0]);      atomicAdd(&f1[r0 + 32], p1[1]);
        atomicAdd(&f2[r0], p2[0]);      atomicAdd(&f2[r0 + 32], p2[1]);
    }
    __syncthreads();
    __hip_bfloat16* xtb = xt + ((size_t)b * FIN + i0) * NN + m0;
    const int mc = (tt & 7) * 8;
    #pragma unroll
    for (int h = 0; h < 2; h++) {
        int ii = (tt >> 3) + h * 32;
        u16x8 v;
        #pragma unroll
        for (int j = 0; j < 8; j++) v[j] = tile[mc + j][ii];
        *(u16x8*)(xtb + (size_t)ii * NN + mc) = v;
    }

    __syncthreads();   // tile LDS is dead; reuse as predicate staging
    {
        // Phase B: convert the (long-since-landed) adj registers to
        // predicate bytes in LDS, then pack (verified k_pack bit layout).
        #pragma unroll
        for (int s = 0; s < 16; s++) {
            int4 v = av[s];
            unsigned int pb = (v.x != 0 ? 0x00000001u : 0u)
                            | (v.y != 0 ? 0x00000100u : 0u)
                            | (v.z != 0 ? 0x00010000u : 0u)
                            | (v.w != 0 ? 0x01000000u : 0u);
            pls[s * 256 + tt] = pb;
        }
        __syncthreads();
        const int r = tt >> 5, c0 = tt & 31;
        #pragma unroll
        for (int half = 0; half < 2; half++) {
            const int c = c0 + half * 32;
            const unsigned int* q = pls + r * 512 + c * 8;
            unsigned int bv = 0;
            #pragma unroll
            for (int j = 0; j < 8; j++) {
                unsigned int pb = q[j];
                bv |= (pb         & 1u) << (j * 4 + 0);
                bv |= ((pb >> 8)  & 1u) << (j * 4 + 1);
                bv |= ((pb >> 16) & 1u) << (j * 4 + 2);
                bv |= ((pb >> 24) & 1u) << (j * 4 + 3);
            }
            bits[(size_t)(b * NN + m0 + it * 8 + r) * 64 + c] = bv;
        }
    }
}

// K3: fused attn-gen + GEMM + softmax-normalize + ELU.
// REVERTED to the R4-verified version (NROW=128, grid 256, 1 block/CU).
__global__ __launch_bounds__(512, 2) void k_main(
    const unsigned int* __restrict__ bits, const __hip_bfloat16* __restrict__ xt,
    const float* __restrict__ f1, const float* __restrict__ f2,
    float* __restrict__ out)
{
    const int bx = blockIdx.x;
    const int b = bx & 7, rt = (bx >> 3) & 15, it = bx >> 7;
    const int n0 = rt * NROW;
    const int i0 = it * 256;
    const int tid = threadIdx.x;
    const int lane = tid & 63, wv = tid >> 6;
    const int quad = lane >> 4, l15 = lane & 15;

    // A tile: [row][octet ^ (row&7)] u16, row stride 64 (128B) — verified swizzle.
    __shared__ u16 At[2][NROW * 64];     // 2 x 16 KB
    __shared__ float rs[NROW];

    // --- gen role: thread -> (row = tid>>2, m-quarter q4 = tid&3, 16 m each) ---
    const int grow = tid >> 2;           // 0..127
    const int q4   = tid & 3;
    const unsigned short* bp = (const unsigned short*)bits
                               + ((size_t)(b * NN) + n0 + grow) * 128 + q4;  // +4 per interval
    const float* f2p = f2 + b * NN + q4 * 16;                                 // +64 per interval
    const float  f1v = f1[b * NN + n0 + grow];
    const int swz = grow & 7;
    u16* wp0 = &At[0][grow * 64 + (((q4 * 2) ^ swz) * 8)];
    u16* wp1 = &At[0][grow * 64 + (((q4 * 2 + 1) ^ swz) * 8)];
    float rpart = 0.f;

    // --- MFMA role: wave wv owns i-cols [i0 + wv*32, +32), 2 col-tiles ---
    const __hip_bfloat16* xtp = xt + ((size_t)(b * FIN) + i0 + wv * 32 + l15) * NN + quad * 8;

    f32x4 acc[8][2];
    #pragma unroll
    for (int s = 0; s < 8; s++) { acc[s][0] = (f32x4){0,0,0,0}; acc[s][1] = (f32x4){0,0,0,0}; }

    auto gen = [&](int buf, unsigned int bv, const f32x4* fr) {
        u16x8 pk0, pk1;
        #pragma unroll
        for (int e = 0; e < 16; e++) {
            float s  = f1v + fr[e >> 2][e & 3];
            float ls = fmaxf(s, GALPHA * s);                 // leaky_relu
            float ev = ((bv >> e) & 1u) ? __expf(ls) : 0.f;
            u16 hb = f2bf(ev);
            rpart += bf2f(hb);                               // rowsum of bf16-rounded
            if (e < 8) pk0[e] = hb; else pk1[e - 8] = hb;
        }
        *(u16x8*)(wp0 + buf * (NROW * 64)) = pk0;
        *(u16x8*)(wp1 + buf * (NROW * 64)) = pk1;
    };

    // prologue: gen tile 0 (direct loads); prime rings for tiles 1,2; B for t=0
    {
        unsigned int b0 = bp[0];
        f32x4 g0[4];
        #pragma unroll
        for (int j = 0; j < 4; j++) g0[j] = *(const f32x4*)(f2p + j * 4);
        gen(0, b0, g0);
    }
    unsigned int brng[2];
    f32x4 frng[2][4];
    brng[1] = bp[4];
    #pragma unroll
    for (int j = 0; j < 4; j++) frng[1][j] = *(const f32x4*)(f2p + 64 + j * 4);
    brng[0] = bp[8];
    #pragma unroll
    for (int j = 0; j < 4; j++) frng[0][j] = *(const f32x4*)(f2p + 128 + j * 4);

    bf16x8 Bc[2][2], Bn[2][2];
    #pragma unroll
    for (int ks = 0; ks < 2; ks++)
        #pragma unroll
        for (int c = 0; c < 2; c++)
            Bc[ks][c] = *(const bf16x8*)(xtp + ks * 32 + (size_t)(c * 16) * NN);
    __syncthreads();

    #pragma unroll 2
    for (int t = 0; t < NIT; t++) {
        const int cur = t & 1;
        if (t < NIT - 1) {   // B prefetch for t+1 (consumed after next barrier)
            const __hip_bfloat16* xk = xtp + (t + 1) * 64;
            #pragma unroll
            for (int ks = 0; ks < 2; ks++)
                #pragma unroll
                for (int c = 0; c < 2; c++)
                    Bn[ks][c] = *(const bf16x8*)(xk + ks * 32 + (size_t)(c * 16) * NN);
        }
        #pragma unroll
        for (int ks = 0; ks < 2; ks++) {
            #pragma unroll
            for (int s = 0; s < 8; s++) {
                const int row = s * 16 + l15;
                bf16x8 Af = *(const bf16x8*)&At[cur][row * 64 + (((ks * 4 + quad) ^ (row & 7)) * 8)];
                acc[s][0] = __builtin_amdgcn_mfma_f32_16x16x32_bf16(Af, Bc[ks][0], acc[s][0], 0, 0, 0);
                acc[s][1] = __builtin_amdgcn_mfma_f32_16x16x32_bf16(Af, Bc[ks][1], acc[s][1], 0, 0, 0);
            }
        }
        if (t < NIT - 1) {
            gen(1 - cur, brng[(t + 1) & 1], frng[(t + 1) & 1]);   // tile t+1
            if (t < NIT - 2) {                                    // refill ring: tile t+2
                brng[t & 1] = bp[(t + 2) * 4];
                #pragma unroll
                for (int j = 0; j < 4; j++)
                    frng[t & 1][j] = *(const f32x4*)(f2p + (t + 2) * 64 + j * 4);
            }
        }
        // LDS-only barrier: global prefetches stay in flight (no vmcnt drain)
        asm volatile("s_waitcnt lgkmcnt(0)\ns_barrier" ::: "memory");
        #pragma unroll
        for (int ks = 0; ks < 2; ks++) {
            Bc[ks][0] = Bn[ks][0]; Bc[ks][1] = Bn[ks][1];
        }
    }

    // rowsum: reduce over the 4 m-quarter threads of each row
    rpart += __shfl_xor(rpart, 1);
    rpart += __shfl_xor(rpart, 2);
    if (q4 == 0) rs[grow] = 1.0f / rpart;
    __syncthreads();

    // epilogue: normalize, ELU, store fp32
    #pragma unroll
    for (int s = 0; s < 8; s++) {
        #pragma unroll
        for (int r = 0; r < 4; r++) {
            const int row = s * 16 + quad * 4 + r;
            const float inv = rs[row];
            float* op = out + ((size_t)b * NN + (n0 + row)) * FIN + i0 + wv * 32 + l15;
            #pragma unroll
            for (int c = 0; c < 2; c++) {
                float v = acc[s][c][r] * inv;
                v = v > 0.f ? v : (__expf(v) - 1.f);   // elu
                op[c * 16] = v;
            }
        }
    }
}

extern "C" void kernel_launch(void* const* d_in, const int* in_sizes, int n_in,
                              void* d_out, int out_size, void* d_ws, size_t ws_size,
                              hipStream_t stream) {
    const float* x   = (const float*)d_in[0];
    const int*   adj = (const int*)d_in[1];
    const float* Wfc = (const float*)d_in[2];
    const float* Wat = (const float*)d_in[3];
    float* out = (float*)d_out;

    float* f1 = (float*)d_ws;                                   // 16384
    float* f2 = f1 + BATCH * NN;                                // 16384
    unsigned int* bits = (unsigned int*)(f2 + BATCH * NN);      // 16384*64 u32 = 4.2 MB
    __hip_bfloat16* xt = (__hip_bfloat16*)(bits + (size_t)BATCH * NN * 64);  // 16.8 MB

    hipMemsetAsync(f1, 0, (size_t)2 * BATCH * NN * sizeof(float), stream);
    hipLaunchKernelGGL(k_prep, dim3(2048), dim3(256), 0, stream,
                       x, adj, Wfc, Wat, xt, f1, f2, bits);
    hipLaunchKernelGGL(k_main, dim3(256),  dim3(512), 0, stream,
                       bits, xt, f1, f2, out);
}